// Round 1
// baseline (492.779 us; speedup 1.0000x reference)
//
#include <hip/hip_runtime.h>

// Grid geometry (compile-time constants for this problem)
#define NB   2
#define NPTS 160
#define NI   156                 // interior points per axis (160-4)
#define OZ   3                   // element stride along z (C=3 fastest)
#define OY   480                 // 160*3
#define OX   76800               // 160*480
#define SB   12288000            // 160*76800
#define PLANE_ELEMS (NI*NI)      // 24336 (j,k) points per (b,i) plane
#define CHUNKS_PER_PLANE 96      // ceil(24336/256)
#define N_PLANES (NB*NI)         // 312
#define INV_SIZE (1.0f/22778496.0f)  // 2*156^3*3

__device__ __forceinline__ void ld3(const float* __restrict__ p,
                                    float& a, float& b, float& c) {
    float v[3];
    __builtin_memcpy(v, p, 12);
    a = v[0]; b = v[1]; c = v[2];
}
__device__ __forceinline__ void ld2(const float* __restrict__ p,
                                    float& a, float& b) {
    float v[2];
    __builtin_memcpy(v, p, 8);
    a = v[0]; b = v[1];
}

__global__ __launch_bounds__(256)
void bending_energy_kernel(const float* __restrict__ g, float* __restrict__ out) {
    const int lin   = blockIdx.x;
    const int plane = lin / CHUNKS_PER_PLANE;          // 0..311
    const int craw  = lin - plane * CHUNKS_PER_PLANE;  // 0..95
    // XCD swizzle: linear%8 == craw&7 selects XCD; give each XCD a
    // contiguous j-slab of the plane for L2 halo reuse.
    const int chunk = (craw & 7) * 12 + (craw >> 3);
    const int t     = chunk * 256 + (int)threadIdx.x;

    float s = 0.0f;
    if (t < PLANE_ELEMS) {
        const int j = t / NI;
        const int k = t - j * NI;
        const int b = plane / NI;
        const int i = plane - b * NI;

        const float* p = g + (size_t)b * SB + (size_t)(i + 2) * OX
                           + (size_t)(j + 2) * OY + (size_t)(k + 2) * OZ;

        // ---- loads (19 vector loads, 47 scalars, zero waste) ----
        float c0, c1, c2;          ld3(p, c0, c1, c2);                 // center
        float xp0 = p[ 2*OX];                                          // +2ex (c0)
        float xm0 = p[-2*OX];                                          // -2ex (c0)
        float yp0, yp1;            ld2(p + 2*OY, yp0, yp1);            // +2ey (c0,c1)
        float ym0, ym1;            ld2(p - 2*OY, ym0, ym1);            // -2ey
        float zp0, zp1, zp2;       ld3(p + 2*OZ, zp0, zp1, zp2);       // +2ez (c0,c1,c2)
        float zm0, zm1, zm2;       ld3(p - 2*OZ, zm0, zm1, zm2);       // -2ez

        // mixed xy corners (c0,c1)
        float xypp0, xypp1;        ld2(p + OX + OY, xypp0, xypp1);
        float xypm0, xypm1;        ld2(p + OX - OY, xypm0, xypm1);
        float xymp0, xymp1;        ld2(p - OX + OY, xymp0, xymp1);
        float xymm0, xymm1;        ld2(p - OX - OY, xymm0, xymm1);
        // mixed xz corners (c0,c1,c2)
        float xzpp0, xzpp1, xzpp2; ld3(p + OX + OZ, xzpp0, xzpp1, xzpp2);
        float xzpm0, xzpm1, xzpm2; ld3(p + OX - OZ, xzpm0, xzpm1, xzpm2);
        float xzmp0, xzmp1, xzmp2; ld3(p - OX + OZ, xzmp0, xzmp1, xzmp2);
        float xzmm0, xzmm1, xzmm2; ld3(p - OX - OZ, xzmm0, xzmm1, xzmm2);
        // mixed yz corners (c0,c1,c2)
        float yzpp0, yzpp1, yzpp2; ld3(p + OY + OZ, yzpp0, yzpp1, yzpp2);
        float yzpm0, yzpm1, yzpm2; ld3(p + OY - OZ, yzpm0, yzpm1, yzpm2);
        float yzmp0, yzmp1, yzmp2; ld3(p - OY + OZ, yzmp0, yzmp1, yzmp2);
        float yzmm0, yzmm1, yzmm2; ld3(p - OY - OZ, yzmm0, yzmm1, yzmm2);

        // ---- raw stencils (scale 0.25^2 = 0.0625 folded into weights) ----
        // pure second derivatives: a - 2c + b
        float hxx0 = xp0 - 2.0f*c0 + xm0;   // w=1
        float hyy0 = yp0 - 2.0f*c0 + ym0;   // w=2
        float hzz0 = zp0 - 2.0f*c0 + zm0;   // w=2
        float hyy1 = yp1 - 2.0f*c1 + ym1;   // w=1
        float hzz1 = zp1 - 2.0f*c1 + zm1;   // w=2
        float hzz2 = zp2 - 2.0f*c2 + zm2;   // w=1
        // mixed: pp - pm - mp + mm
        float hxy0 = (xypp0 - xypm0) - (xymp0 - xymm0);  // w=3
        float hxy1 = (xypp1 - xypm1) - (xymp1 - xymm1);  // w=1
        float hxz0 = (xzpp0 - xzpm0) - (xzmp0 - xzmm0);  // w=3
        float hxz1 = (xzpp1 - xzpm1) - (xzmp1 - xzmm1);  // w=2
        float hxz2 = (xzpp2 - xzpm2) - (xzmp2 - xzmm2);  // w=1
        float hyz0 = (yzpp0 - yzpm0) - (yzmp0 - yzmm0);  // w=4
        float hyz1 = (yzpp1 - yzpm1) - (yzmp1 - yzmm1);  // w=3
        float hyz2 = (yzpp2 - yzpm2) - (yzmp2 - yzmm2);  // w=1

        const float W1 = 1.0f * 0.0625f;
        const float W2 = 2.0f * 0.0625f;
        const float W3 = 3.0f * 0.0625f;
        const float W4 = 4.0f * 0.0625f;

        s = fmaf(W1*hxx0, hxx0, s);
        s = fmaf(W2*hyy0, hyy0, s);
        s = fmaf(W2*hzz0, hzz0, s);
        s = fmaf(W1*hyy1, hyy1, s);
        s = fmaf(W2*hzz1, hzz1, s);
        s = fmaf(W1*hzz2, hzz2, s);
        s = fmaf(W3*hxy0, hxy0, s);
        s = fmaf(W1*hxy1, hxy1, s);
        s = fmaf(W3*hxz0, hxz0, s);
        s = fmaf(W2*hxz1, hxz1, s);
        s = fmaf(W1*hxz2, hxz2, s);
        s = fmaf(W4*hyz0, hyz0, s);
        s = fmaf(W3*hyz1, hyz1, s);
        s = fmaf(W1*hyz2, hyz2, s);
    }

    // ---- reduction: wave shfl -> LDS -> one atomic per block ----
    #pragma unroll
    for (int off = 32; off > 0; off >>= 1)
        s += __shfl_down(s, off, 64);

    __shared__ float ws[4];
    const int lane = threadIdx.x & 63;
    const int wid  = threadIdx.x >> 6;
    if (lane == 0) ws[wid] = s;
    __syncthreads();
    if (threadIdx.x == 0) {
        float tot = (ws[0] + ws[1]) + (ws[2] + ws[3]);
        atomicAdd(out, tot * INV_SIZE);
    }
}

extern "C" void kernel_launch(void* const* d_in, const int* in_sizes, int n_in,
                              void* d_out, int out_size, void* d_ws, size_t ws_size,
                              hipStream_t stream) {
    const float* grid = (const float*)d_in[0];
    float* out = (float*)d_out;

    hipMemsetAsync(out, 0, sizeof(float), stream);

    dim3 block(256);
    dim3 grid_dim(CHUNKS_PER_PLANE * N_PLANES);  // 96 * 312 = 29952 blocks
    bending_energy_kernel<<<grid_dim, block, 0, stream>>>(grid, out);
}

// Round 2
// 236.587 us; speedup vs baseline: 2.0829x; 2.0829x over previous
//
#include <hip/hip_runtime.h>

// Geometry: grid [2,160,160,160,3] fp32, interior 156^3 per batch.
#define NI 156
#define OZ 3
#define OY 480                     // 160*3
#define OX 76800                   // 160*480
#define SB 12288000                // 160*76800
#define KQ 39                      // 156/4 k-chunks per row (4 points/thread)
#define NWORK (2*NI*NI*KQ)         // 1,898,208 work items
#define NBLK ((NWORK + 255)/256)   // 7,415 blocks
#define INV_SIZE (1.0f/22778496.0f)  // 2*156^3*3

template<int N>
__device__ __forceinline__ void ldN(float* dst, const float* __restrict__ src) {
    __builtin_memcpy(dst, src, N * 4);
}

// Per-thread: 4 consecutive k points, 13 contiguous row-span loads issued
// up-front (max MLP), stencils folded with composed-central-diff weights.
template<bool USE_ATOMIC>
__global__ __launch_bounds__(256)
void be_partials(const float* __restrict__ g, float* __restrict__ partial) {
    const int t = blockIdx.x * 256 + (int)threadIdx.x;
    float s = 0.0f;
    if (t < NWORK) {
        const int kq = t % KQ;
        const int r  = t / KQ;
        const int j  = r % NI;
        const int r2 = r / NI;
        const int i  = r2 % NI;
        const int b  = r2 / NI;
        // P -> comp0 of z index (kq*4 + 2): center of point q=0
        const float* P = g + (size_t)b * SB + (size_t)(i + 2) * OX
                           + (size_t)(j + 2) * OY + (size_t)(kq * 4 + 2) * OZ;

        // ---- all loads issued before any use ----
        float m[24], xp[10], xm[10], yp[11], ym[11];
        float xypp[11], xypm[11], xymp[11], xymm[11];
        float xzp[18], xzm[18], yzp[18], yzm[18];
        ldN<24>(m,    P - 6);              // row (i,j): covers zm..zp for 4 pts
        ldN<10>(xp,   P + 2*OX);           // (i+2,j) comp0
        ldN<10>(xm,   P - 2*OX);           // (i-2,j) comp0
        ldN<11>(yp,   P + 2*OY);           // (i,j+2) comps 0,1
        ldN<11>(ym,   P - 2*OY);           // (i,j-2)
        ldN<11>(xypp, P + OX + OY);        // xy corners, comps 0,1
        ldN<11>(xypm, P + OX - OY);
        ldN<11>(xymp, P - OX + OY);
        ldN<11>(xymm, P - OX - OY);
        ldN<18>(xzp,  P + OX - 3);         // (i+1,j) z-1..z+4, comps 0..2
        ldN<18>(xzm,  P - OX - 3);
        ldN<18>(yzp,  P + OY - 3);         // (i,j+1) z-1..z+4, comps 0..2
        ldN<18>(yzm,  P - OY - 3);

        // weights: (term multiplicity) * 0.25^2  (two composed 0.5-central diffs)
        const float W1 = 0.0625f, W2 = 0.125f, W3 = 0.1875f, W4 = 0.25f;
        #pragma unroll
        for (int q = 0; q < 4; ++q) {
            const int o = 3 * q;
            const float c0 = m[o+6], c1 = m[o+7], c2 = m[o+8];
            float hzz0 = m[o+12] - 2.0f*c0 + m[o];
            float hzz1 = m[o+13] - 2.0f*c1 + m[o+1];
            float hzz2 = m[o+14] - 2.0f*c2 + m[o+2];
            float hxx0 = xp[o]   - 2.0f*c0 + xm[o];
            float hyy0 = yp[o]   - 2.0f*c0 + ym[o];
            float hyy1 = yp[o+1] - 2.0f*c1 + ym[o+1];
            float hxy0 = (xypp[o]   - xypm[o])   - (xymp[o]   - xymm[o]);
            float hxy1 = (xypp[o+1] - xypm[o+1]) - (xymp[o+1] - xymm[o+1]);
            float hxz0 = (xzp[o+6] - xzp[o])   - (xzm[o+6] - xzm[o]);
            float hxz1 = (xzp[o+7] - xzp[o+1]) - (xzm[o+7] - xzm[o+1]);
            float hxz2 = (xzp[o+8] - xzp[o+2]) - (xzm[o+8] - xzm[o+2]);
            float hyz0 = (yzp[o+6] - yzp[o])   - (yzm[o+6] - yzm[o]);
            float hyz1 = (yzp[o+7] - yzp[o+1]) - (yzm[o+7] - yzm[o+1]);
            float hyz2 = (yzp[o+8] - yzp[o+2]) - (yzm[o+8] - yzm[o+2]);
            s = fmaf(W1*hxx0, hxx0, s);
            s = fmaf(W2*hyy0, hyy0, s);
            s = fmaf(W2*hzz0, hzz0, s);
            s = fmaf(W1*hyy1, hyy1, s);
            s = fmaf(W2*hzz1, hzz1, s);
            s = fmaf(W1*hzz2, hzz2, s);
            s = fmaf(W3*hxy0, hxy0, s);
            s = fmaf(W1*hxy1, hxy1, s);
            s = fmaf(W3*hxz0, hxz0, s);
            s = fmaf(W2*hxz1, hxz1, s);
            s = fmaf(W1*hxz2, hxz2, s);
            s = fmaf(W4*hyz0, hyz0, s);
            s = fmaf(W3*hyz1, hyz1, s);
            s = fmaf(W1*hyz2, hyz2, s);
        }
    }

    // block reduction: wave shfl -> LDS -> one store (or atomic fallback)
    #pragma unroll
    for (int off = 32; off > 0; off >>= 1) s += __shfl_down(s, off, 64);
    __shared__ float ws4[4];
    if ((threadIdx.x & 63) == 0) ws4[threadIdx.x >> 6] = s;
    __syncthreads();
    if (threadIdx.x == 0) {
        const float tot = (ws4[0] + ws4[1]) + (ws4[2] + ws4[3]);
        if (USE_ATOMIC) atomicAdd(partial, tot * INV_SIZE);
        else            partial[blockIdx.x] = tot;
    }
}

__global__ __launch_bounds__(256)
void be_final(const float* __restrict__ partial, float* __restrict__ out, int n) {
    float s = 0.0f;
    for (int idx = threadIdx.x; idx < n; idx += 256) s += partial[idx];
    #pragma unroll
    for (int off = 32; off > 0; off >>= 1) s += __shfl_down(s, off, 64);
    __shared__ float ws4[4];
    if ((threadIdx.x & 63) == 0) ws4[threadIdx.x >> 6] = s;
    __syncthreads();
    if (threadIdx.x == 0)
        out[0] = ((ws4[0] + ws4[1]) + (ws4[2] + ws4[3])) * INV_SIZE;
}

extern "C" void kernel_launch(void* const* d_in, const int* in_sizes, int n_in,
                              void* d_out, int out_size, void* d_ws, size_t ws_size,
                              hipStream_t stream) {
    const float* grid = (const float*)d_in[0];
    float* out = (float*)d_out;

    if (ws_size >= (size_t)NBLK * sizeof(float)) {
        float* partials = (float*)d_ws;
        be_partials<false><<<NBLK, 256, 0, stream>>>(grid, partials);
        be_final<<<1, 256, 0, stream>>>(partials, out, NBLK);
    } else {
        // fallback: atomic accumulation directly into out
        hipMemsetAsync(out, 0, sizeof(float), stream);
        be_partials<true><<<NBLK, 256, 0, stream>>>(grid, out);
    }
}

// Round 3
// 202.072 us; speedup vs baseline: 2.4386x; 1.1708x over previous
//
#include <hip/hip_runtime.h>

// grid [2,160,160,160,3] fp32; interior 156^3 per batch.
#define NI 156
#define OZ 3
#define OY 480                   // 160*3
#define OX 76800                 // 160*480
#define SB 12288000              // 160*76800
#define PLANE (NI*NI)            // 24336 points per (b,i) plane
#define CPP 96                   // chunks/plane: 96*256 = 24576 >= 24336
#define NPLANES (2*NI)           // 312
#define NBLK (CPP*NPLANES)       // 29952 partials
#define INV_SIZE (1.0f/22778496.0f)  // 2*156^3*3

__device__ __forceinline__ void ld3(const float* __restrict__ p,
                                    float& a, float& b, float& c) {
    float v[3]; __builtin_memcpy(v, p, 12); a = v[0]; b = v[1]; c = v[2];
}
__device__ __forceinline__ void ld2(const float* __restrict__ p,
                                    float& a, float& b) {
    float v[2]; __builtin_memcpy(v, p, 8); a = v[0]; b = v[1];
}

// 1 point/thread, lanes consecutive in z (12 B lane stride -> dense wave
// access: ~7 cache lines per load instruction). All 19 loads issued
// before any use for MLP. No global atomic: block partial -> ws.
__global__ __launch_bounds__(256)
void be_partials(const float* __restrict__ g, float* __restrict__ partial) {
    const int tp    = blockIdx.x * 256 + (int)threadIdx.x;  // in-plane index
    const int plane = blockIdx.y;                           // 0..311 (b,i)

    float s = 0.0f;
    if (tp < PLANE) {
        const int j = tp / NI;          // magic-mul div
        const int k = tp - j * NI;
        const int i = plane % NI;       // wave-uniform -> scalar ops
        const int b = plane / NI;

        const float* __restrict__ p = g + (size_t)b * SB + (size_t)(i + 2) * OX
                                        + (size_t)(j + 2) * OY + (size_t)(k + 2) * OZ;

        // ---- 19 loads, 47 floats, all issued up-front ----
        float c0, c1, c2;          ld3(p,        c0, c1, c2);
        float zp0, zp1, zp2;       ld3(p + 2*OZ, zp0, zp1, zp2);
        float zm0, zm1, zm2;       ld3(p - 2*OZ, zm0, zm1, zm2);
        float xp0 = p[ 2*OX];
        float xm0 = p[-2*OX];
        float yp0, yp1;            ld2(p + 2*OY, yp0, yp1);
        float ym0, ym1;            ld2(p - 2*OY, ym0, ym1);
        float xypp0, xypp1;        ld2(p + OX + OY, xypp0, xypp1);
        float xypm0, xypm1;        ld2(p + OX - OY, xypm0, xypm1);
        float xymp0, xymp1;        ld2(p - OX + OY, xymp0, xymp1);
        float xymm0, xymm1;        ld2(p - OX - OY, xymm0, xymm1);
        float xzpp0, xzpp1, xzpp2; ld3(p + OX + OZ, xzpp0, xzpp1, xzpp2);
        float xzpm0, xzpm1, xzpm2; ld3(p + OX - OZ, xzpm0, xzpm1, xzpm2);
        float xzmp0, xzmp1, xzmp2; ld3(p - OX + OZ, xzmp0, xzmp1, xzmp2);
        float xzmm0, xzmm1, xzmm2; ld3(p - OX - OZ, xzmm0, xzmm1, xzmm2);
        float yzpp0, yzpp1, yzpp2; ld3(p + OY + OZ, yzpp0, yzpp1, yzpp2);
        float yzpm0, yzpm1, yzpm2; ld3(p + OY - OZ, yzpm0, yzpm1, yzpm2);
        float yzmp0, yzmp1, yzmp2; ld3(p - OY + OZ, yzmp0, yzmp1, yzmp2);
        float yzmm0, yzmm1, yzmm2; ld3(p - OY - OZ, yzmm0, yzmm1, yzmm2);

        // ---- stencils ----
        float hxx0 = xp0 - 2.0f*c0 + xm0;                      // w1
        float hyy0 = yp0 - 2.0f*c0 + ym0;                      // w2
        float hzz0 = zp0 - 2.0f*c0 + zm0;                      // w2
        float hyy1 = yp1 - 2.0f*c1 + ym1;                      // w1
        float hzz1 = zp1 - 2.0f*c1 + zm1;                      // w2
        float hzz2 = zp2 - 2.0f*c2 + zm2;                      // w1
        float hxy0 = (xypp0 - xypm0) - (xymp0 - xymm0);        // w3
        float hxy1 = (xypp1 - xypm1) - (xymp1 - xymm1);        // w1
        float hxz0 = (xzpp0 - xzpm0) - (xzmp0 - xzmm0);        // w3
        float hxz1 = (xzpp1 - xzpm1) - (xzmp1 - xzmm1);        // w2
        float hxz2 = (xzpp2 - xzpm2) - (xzmp2 - xzmm2);        // w1
        float hyz0 = (yzpp0 - yzpm0) - (yzmp0 - yzmm0);        // w4
        float hyz1 = (yzpp1 - yzpm1) - (yzmp1 - yzmm1);        // w3
        float hyz2 = (yzpp2 - yzpm2) - (yzmp2 - yzmm2);        // w1

        // ---- shared-weight grouping: sum-of-squares per weight class ----
        float a1 = hxx0*hxx0;
        a1 = fmaf(hyy1, hyy1, a1); a1 = fmaf(hzz2, hzz2, a1);
        a1 = fmaf(hxy1, hxy1, a1); a1 = fmaf(hxz2, hxz2, a1);
        a1 = fmaf(hyz2, hyz2, a1);
        float a2 = hyy0*hyy0;
        a2 = fmaf(hzz0, hzz0, a2); a2 = fmaf(hzz1, hzz1, a2);
        a2 = fmaf(hxz1, hxz1, a2);
        float a3 = hxy0*hxy0;
        a3 = fmaf(hxz0, hxz0, a3); a3 = fmaf(hyz1, hyz1, a3);
        float a4 = hyz0*hyz0;

        float t = fmaf(2.0f, a2, a1);
        t = fmaf(3.0f, a3, t);
        t = fmaf(4.0f, a4, t);
        s = 0.0625f * t;
    }

    // ---- block reduction: wave shfl -> LDS -> one store per block ----
    #pragma unroll
    for (int off = 32; off > 0; off >>= 1) s += __shfl_down(s, off, 64);
    __shared__ float ws4[4];
    if ((threadIdx.x & 63) == 0) ws4[threadIdx.x >> 6] = s;
    __syncthreads();
    if (threadIdx.x == 0)
        partial[blockIdx.y * CPP + blockIdx.x] = (ws4[0] + ws4[1]) + (ws4[2] + ws4[3]);
}

__global__ __launch_bounds__(1024)
void be_final(const float* __restrict__ partial, float* __restrict__ out) {
    float s = 0.0f;
    #pragma unroll 4
    for (int idx = threadIdx.x; idx < NBLK; idx += 1024) s += partial[idx];
    #pragma unroll
    for (int off = 32; off > 0; off >>= 1) s += __shfl_down(s, off, 64);
    __shared__ float ws[16];
    if ((threadIdx.x & 63) == 0) ws[threadIdx.x >> 6] = s;
    __syncthreads();
    if (threadIdx.x == 0) {
        float tot = 0.0f;
        #pragma unroll
        for (int w = 0; w < 16; ++w) tot += ws[w];
        out[0] = tot * INV_SIZE;
    }
}

extern "C" void kernel_launch(void* const* d_in, const int* in_sizes, int n_in,
                              void* d_out, int out_size, void* d_ws, size_t ws_size,
                              hipStream_t stream) {
    const float* grid = (const float*)d_in[0];
    float* out = (float*)d_out;
    float* partials = (float*)d_ws;   // NBLK floats = 117 KB, fits any ws

    dim3 grid_dim(CPP, NPLANES);      // 96 x 312
    be_partials<<<grid_dim, dim3(256), 0, stream>>>(grid, partials);
    be_final<<<1, 1024, 0, stream>>>(partials, out);
}

// Round 4
// 169.679 us; speedup vs baseline: 2.9042x; 1.1909x over previous
//
#include <hip/hip_runtime.h>

// grid [2,160,160,160,3] fp32; interior 156^3 per batch.
#define OY 480                    // 160*3
#define OX 76800                  // 160*480
#define SB 12288000               // 160*76800
#define JT 12                     // interior j per block (13 tiles)
#define KT 39                     // interior k per block (4 tiles)
#define IT 39                     // interior i marched per block (4 segs)
#define NBLK 416                  // 2 * 13 * 4 * 4
#define ROWF 129                  // floats per staged row: 43 z * 3 comps
#define RW 132                    // padded LDS row stride (floats)
#define NROW 16                   // JT + 4 halo rows
#define SLICE (NROW*RW)           // 2112 floats per slice buffer
#define NBUF 6                    // rolling slice buffers (1 barrier/step safe)
#define SLICE_FLOATS (NROW*ROWF)  // 2064 floats actually staged
#define PTS (JT*KT)               // 468 points per i-step
#define INV_SIZE (1.0f/22778496.0f)  // 2*156^3*3

// Block: 512 threads. Marches i over IT slices; per step stages one new
// (16 row x 129 float) slice into a 6-deep LDS ring and computes 468
// stencil points from the 5 center slices. Global data read once per
// block as dense dwords; stencil served from LDS.
__global__ __launch_bounds__(512)
void be_partials(const float* __restrict__ g, float* __restrict__ partial) {
    __shared__ float lds[NBUF * SLICE];
    __shared__ float wsum[8];

    const int tid = threadIdx.x;
    const int bid = blockIdx.x;
    const int kt  = bid & 3;
    const int is  = (bid >> 2) & 3;
    const int r   = bid >> 4;          // 0..25
    const int jt  = r % 13;
    const int bb  = r / 13;

    const int j0  = jt * JT;           // global rows j0..j0+15
    const int k0z = kt * KT;           // global z k0z..k0z+42
    const int ib  = is * IT;           // global x slices ib..ib+42

    const float* __restrict__ G = g + (size_t)bb * SB;

    // ---- fixed per-thread staging offsets (4 + optional tail) ----
    int gd0, gd1, gd2, gd3, gd4 = 0, ld0, ld1, ld2, ld3, ld4 = 0;
    {
        int f, row, pos;
        f = tid;        row = f / ROWF; pos = f - row * ROWF;
        gd0 = (j0 + row) * OY + k0z * 3 + pos;  ld0 = row * RW + pos;
        f = tid + 512;  row = f / ROWF; pos = f - row * ROWF;
        gd1 = (j0 + row) * OY + k0z * 3 + pos;  ld1 = row * RW + pos;
        f = tid + 1024; row = f / ROWF; pos = f - row * ROWF;
        gd2 = (j0 + row) * OY + k0z * 3 + pos;  ld2 = row * RW + pos;
        f = tid + 1536; row = f / ROWF; pos = f - row * ROWF;
        gd3 = (j0 + row) * OY + k0z * 3 + pos;  ld3 = row * RW + pos;
    }
    const bool tail = (tid < SLICE_FLOATS - 2048);   // 16 threads
    if (tail) {
        int f = tid + 2048; int row = f / ROWF; int pos = f - row * ROWF;
        gd4 = (j0 + row) * OY + k0z * 3 + pos;  ld4 = row * RW + pos;
    }

    // ---- compute-point mapping ----
    const bool act = tid < PTS;
    int jj = tid / KT;
    int kk = tid - jj * KT;
    if (!act) { jj = 0; kk = 0; }
    const int cbase = (jj + 2) * RW + (kk + 2) * 3;   // center comp0 (in-slice)

    // ---- warmup: stage slices ib..ib+4 ----
    #pragma unroll
    for (int w = 0; w < 5; ++w) {
        const int x = ib + w;
        const float* base = G + (size_t)x * OX;
        float a0 = base[gd0], a1 = base[gd1], a2 = base[gd2], a3 = base[gd3];
        float a4 = tail ? base[gd4] : 0.0f;
        float* L = lds + (x % NBUF) * SLICE;
        L[ld0] = a0; L[ld1] = a1; L[ld2] = a2; L[ld3] = a3;
        if (tail) L[ld4] = a4;
    }
    __syncthreads();

    float s = 0.0f;
    for (int i0 = ib; i0 < ib + IT; ++i0) {
        // 1) issue next slice's global loads (one step ahead of use)
        const int xn = i0 + 5;
        const bool doLoad = (xn <= ib + 42);
        float a0 = 0.f, a1 = 0.f, a2 = 0.f, a3 = 0.f, a4 = 0.f;
        if (doLoad) {
            const float* base = G + (size_t)xn * OX;
            a0 = base[gd0]; a1 = base[gd1]; a2 = base[gd2]; a3 = base[gd3];
            if (tail) a4 = base[gd4];
        }

        // 2) compute current i0 from slices x = i0..i0+4 (buffers x%6)
        if (act) {
            int s0 = i0 % NBUF;
            int s1 = s0 + 1; if (s1 >= NBUF) s1 -= NBUF;
            int s2 = s1 + 1; if (s2 >= NBUF) s2 -= NBUF;
            int s3 = s2 + 1; if (s3 >= NBUF) s3 -= NBUF;
            int s4 = s3 + 1; if (s4 >= NBUF) s4 -= NBUF;
            const float* Sm2 = lds + s0 * SLICE + cbase;  // x = i0   (di=-2)
            const float* Sm1 = lds + s1 * SLICE + cbase;  // di=-1
            const float* Sc  = lds + s2 * SLICE + cbase;  // center
            const float* Sp1 = lds + s3 * SLICE + cbase;  // di=+1
            const float* Sp2 = lds + s4 * SLICE + cbase;  // di=+2

            const float c0 = Sc[0], c1 = Sc[1], c2 = Sc[2];
            float hzz0 = Sc[6] - 2.0f*c0 + Sc[-6];
            float hzz1 = Sc[7] - 2.0f*c1 + Sc[-5];
            float hzz2 = Sc[8] - 2.0f*c2 + Sc[-4];
            float hyy0 = Sc[ 2*RW]     - 2.0f*c0 + Sc[-2*RW];
            float hyy1 = Sc[ 2*RW + 1] - 2.0f*c1 + Sc[-2*RW + 1];
            float hxx0 = Sp2[0] - 2.0f*c0 + Sm2[0];
            float hyz0 = (Sc[RW+3] - Sc[RW-3]) - (Sc[-RW+3] - Sc[-RW-3]);
            float hyz1 = (Sc[RW+4] - Sc[RW-2]) - (Sc[-RW+4] - Sc[-RW-2]);
            float hyz2 = (Sc[RW+5] - Sc[RW-1]) - (Sc[-RW+5] - Sc[-RW-1]);
            float hxy0 = (Sp1[ RW]   - Sp1[-RW])   - (Sm1[ RW]   - Sm1[-RW]);
            float hxy1 = (Sp1[ RW+1] - Sp1[-RW+1]) - (Sm1[ RW+1] - Sm1[-RW+1]);
            float hxz0 = (Sp1[3] - Sp1[-3]) - (Sm1[3] - Sm1[-3]);
            float hxz1 = (Sp1[4] - Sp1[-2]) - (Sm1[4] - Sm1[-2]);
            float hxz2 = (Sp1[5] - Sp1[-1]) - (Sm1[5] - Sm1[-1]);

            // weight classes (multiplicity * 0.0625 folded at the end)
            float w1 = hxx0*hxx0;
            w1 = fmaf(hyy1, hyy1, w1); w1 = fmaf(hzz2, hzz2, w1);
            w1 = fmaf(hxy1, hxy1, w1); w1 = fmaf(hxz2, hxz2, w1);
            w1 = fmaf(hyz2, hyz2, w1);
            float w2 = hyy0*hyy0;
            w2 = fmaf(hzz0, hzz0, w2); w2 = fmaf(hzz1, hzz1, w2);
            w2 = fmaf(hxz1, hxz1, w2);
            float w3 = hxy0*hxy0;
            w3 = fmaf(hxz0, hxz0, w3); w3 = fmaf(hyz1, hyz1, w3);
            float w4 = hyz0*hyz0;

            float t = fmaf(2.0f, w2, w1);
            t = fmaf(3.0f, w3, t);
            t = fmaf(4.0f, w4, t);
            s = fmaf(0.0625f, t, s);
        }

        // 3) retire staged slice into ring buffer (xn%6 not read this step)
        if (doLoad) {
            float* L = lds + (xn % NBUF) * SLICE;
            L[ld0] = a0; L[ld1] = a1; L[ld2] = a2; L[ld3] = a3;
            if (tail) L[ld4] = a4;
        }
        __syncthreads();
    }

    // ---- block reduction ----
    #pragma unroll
    for (int off = 32; off > 0; off >>= 1) s += __shfl_down(s, off, 64);
    if ((tid & 63) == 0) wsum[tid >> 6] = s;
    __syncthreads();
    if (tid == 0) {
        float tot = 0.0f;
        #pragma unroll
        for (int w = 0; w < 8; ++w) tot += wsum[w];
        partial[bid] = tot;
    }
}

__global__ __launch_bounds__(256)
void be_final(const float* __restrict__ partial, float* __restrict__ out) {
    float s = 0.0f;
    for (int i = threadIdx.x; i < NBLK; i += 256) s += partial[i];
    #pragma unroll
    for (int off = 32; off > 0; off >>= 1) s += __shfl_down(s, off, 64);
    __shared__ float ws[4];
    if ((threadIdx.x & 63) == 0) ws[threadIdx.x >> 6] = s;
    __syncthreads();
    if (threadIdx.x == 0)
        out[0] = ((ws[0] + ws[1]) + (ws[2] + ws[3])) * INV_SIZE;
}

extern "C" void kernel_launch(void* const* d_in, const int* in_sizes, int n_in,
                              void* d_out, int out_size, void* d_ws, size_t ws_size,
                              hipStream_t stream) {
    const float* grid = (const float*)d_in[0];
    float* out = (float*)d_out;
    float* partials = (float*)d_ws;    // 416 floats

    be_partials<<<dim3(NBLK), dim3(512), 0, stream>>>(grid, partials);
    be_final<<<1, 256, 0, stream>>>(partials, out);
}